// Round 6
// baseline (456.615 us; speedup 1.0000x reference)
//
#include <hip/hip_runtime.h>
#include <cstdint>
#include <cstddef>

// Problem constants: B=4, T=2048, H=1024, NH=16, HD=64, FF=4096, M=B*T=8192
typedef unsigned short u16;
typedef __attribute__((ext_vector_type(8))) __bf16 bf16x8;
typedef __attribute__((ext_vector_type(4))) __bf16 bf16x4;
typedef __attribute__((ext_vector_type(4))) float f32x4;
typedef __attribute__((ext_vector_type(16))) float f32x16;
typedef __attribute__((ext_vector_type(4))) u16 u16x4;

#define MFMA(a, b, c) __builtin_amdgcn_mfma_f32_16x16x32_bf16((a), (b), (c), 0, 0, 0)
#define MFMA32(a, b, c) __builtin_amdgcn_mfma_f32_32x32x16_bf16((a), (b), (c), 0, 0, 0)

__device__ __forceinline__ u16 f2b(float f) {  // native RNE cvt
  union { __bf16 h; u16 u; } v;
  v.h = (__bf16)f;
  return v.u;
}

__device__ __forceinline__ void gld16(const void* g, void* l) {
  __builtin_amdgcn_global_load_lds(
      (__attribute__((address_space(1))) void*)(void*)(g),
      (__attribute__((address_space(3))) void*)(l), 16, 0, 0);
}

// Fragment-ordered layouts (per head, 131072 u16 = 2048x64), 16x16x32 frags:
// Q/K: element (t, hd): chunk ((t>>4)*2 + (hd>>5)), lane ((hd>>3)&3)*16 + (t&15),
//      byte-slot hd&7. MFMA lane l reads its 16B at chunk_base + l*16B.
__device__ __forceinline__ size_t qk_off(int t, int hd) {
  return (size_t)((((t >> 4) * 2 + (hd >> 5)) * 512)
                  + ((((hd >> 3) & 3) * 16 + (t & 15)) * 8) + (hd & 7));
}
// V: keys kk-permuted within 64-groups (kk = (t&15)*4 + ((t>>4)&3)) to match the
//    P-tile LDS packing; fragment order for PV B-operand reads.
__device__ __forceinline__ size_t v_off(int t, int hd) {
  int kk = ((t & 15) << 2) | ((t >> 4) & 3);
  return (size_t)(((t >> 6) * 4096)
                  + (((hd >> 4) * 2 + (kk >> 5)) * 512)
                  + ((((kk >> 3) & 3) * 16 + (hd & 15)) * 8) + (kk & 7));
}

// ---------------------------------------------------------------------------
// ONE prep launch: x->bf16 conversion + all weight transposes.
// Sections (block ids): 0-3071 Wq/Wk/Wv (1024 each) -> Wqkvt stacked;
// 3072-7167 W1; 7168-11263 W2; 11264+ : x fp32 -> bf16 (x4 vectorized).
__global__ void prep_all(const float* __restrict__ x, u16* __restrict__ xb,
                         const float* __restrict__ Wq, const float* __restrict__ Wk,
                         const float* __restrict__ Wv, const float* __restrict__ W1,
                         const float* __restrict__ W2, u16* __restrict__ Wqkvt,
                         u16* __restrict__ W1t, u16* __restrict__ W2t) {
  int blk = blockIdx.x;
  int tx = threadIdx.x, ty = threadIdx.y;
  if (blk >= 11264) {
    int i = ((blk - 11264) * 256 + ty * 32 + tx) * 4;
    float4 v = *(const float4*)(x + i);
    u16x4 o;
    o[0] = f2b(v.x); o[1] = f2b(v.y); o[2] = f2b(v.z); o[3] = f2b(v.w);
    *(u16x4*)(xb + i) = o;
    return;
  }
  __shared__ float tile[32][33];
  const float* W;
  u16* Wt;
  int Kd, Nd, nx;
  if (blk < 3072) {
    int s = blk >> 10;
    blk &= 1023;
    W = (s == 0) ? Wq : (s == 1) ? Wk : Wv;
    Wt = Wqkvt + (size_t)s * 1048576;
    Kd = 1024; Nd = 1024; nx = 32;
  } else if (blk < 7168) {
    blk -= 3072; W = W1; Wt = W1t; Kd = 1024; Nd = 4096; nx = 128;
  } else {
    blk -= 7168; W = W2; Wt = W2t; Kd = 4096; Nd = 1024; nx = 32;
  }
  int n0 = (blk % nx) * 32, k0 = (blk / nx) * 32;
#pragma unroll
  for (int i = 0; i < 4; i++)
    tile[ty + i * 8][tx] = W[(size_t)(k0 + ty + i * 8) * Nd + n0 + tx];
  __syncthreads();
#pragma unroll
  for (int i = 0; i < 4; i++)
    Wt[(size_t)(n0 + ty + i * 8) * Kd + k0 + tx] = f2b(tile[tx][ty + i * 8]);
}

// ---------------------------------------------------------------------------
// C[M,N] = A[M,K] @ Bt[N,K]^T + bias. 128x128 tile, BK=64, 32x32x16 MFMA.
// global_load_lds staging with XOR-swizzled LDS: LDS[row][j] = G[row][j^(row&7)]
// (j = 16B chunk within the 64-elem row); conflict-free staging AND reads.
// NW=4: waves 2x2, each 64x64 (acc 2x2 of 32x32). NW=8: waves 2x4, each 64x32.
// MODE 2: bf16 out = gelu(v), row-major (MLP1)
// MODE 3: fp32 out = v + resid, row-major (MLP2 + residual -> d_out)
// MODE 4: fused QKV, N=3072: sec 0=Q (scaled, frag-order), 1=K (frag-order),
//         2=V (kk-permuted frag-order); K at +8388608 u16, V at +16777216.
template <int MODE, int NW>
__global__ __launch_bounds__(NW * 64) void gemm_bt(
    const u16* __restrict__ A, const u16* __restrict__ Bt,
    const float* __restrict__ b0, const float* __restrict__ b1,
    const float* __restrict__ b2, void* __restrict__ outp,
    const float* __restrict__ resid, int N, int K, float scale) {
  constexpr int NT = NW * 64;
  constexpr int NT32 = (NW == 4) ? 2 : 1;   // 32x32 col-tiles per wave
  __shared__ __attribute__((aligned(16))) u16 As[128 * 64];
  __shared__ __attribute__((aligned(16))) u16 Bs[128 * 64];
  const int tid = threadIdx.x;
  const int wid = tid >> 6, lane = tid & 63;
  const int bm = blockIdx.y, bn = blockIdx.x;
  const int wrow = (NW == 4) ? (wid >> 1) * 64 : (wid >> 2) * 64;
  const int wcol = (NW == 4) ? (wid & 1) * 64 : (wid & 3) * 32;
  const int lrow = lane & 31, hi = lane >> 5, xm = lane & 7;

  f32x16 acc[2][NT32];
#pragma unroll
  for (int i = 0; i < 2; i++)
#pragma unroll
    for (int j = 0; j < NT32; j++)
#pragma unroll
      for (int e = 0; e < 16; e++) acc[i][j][e] = 0.f;

  const size_t aBase = (size_t)bm * 128 * K;
  const size_t bBase = (size_t)bn * 128 * K;
  // fragment row byte-bases (u16 units) into LDS
  const int rA0 = (wrow + lrow) * 64, rA1 = (wrow + 32 + lrow) * 64;
  const int rB0 = (wcol + lrow) * 64, rB1 = (wcol + 32 + lrow) * 64;

  for (int k0 = 0; k0 < K; k0 += 64) {
    __syncthreads();
#pragma unroll
    for (int i = 0; i < 2048 / NT; i++) {
      const int c0 = i * NT;
      const int cc = (c0 + tid) & 1023;
      const int row = cc >> 3;
      const int js = ((cc & 7) ^ (row & 7)) * 8;
      if (c0 < 1024)
        gld16(A + aBase + (size_t)row * K + k0 + js, As + cc * 8);
      else
        gld16(Bt + bBase + (size_t)row * K + k0 + js, Bs + cc * 8);
    }
    __syncthreads();
#pragma unroll
    for (int kc = 0; kc < 4; kc++) {   // 4 k-chunks of 16
      const int co = ((kc * 2 + hi) ^ xm) * 8;
      bf16x8 af[2], bfr[NT32];
      af[0] = *(const bf16x8*)&As[rA0 + co];
      af[1] = *(const bf16x8*)&As[rA1 + co];
      bfr[0] = *(const bf16x8*)&Bs[rB0 + co];
      if (NT32 == 2) bfr[1] = *(const bf16x8*)&Bs[rB1 + co];
#pragma unroll
      for (int mt = 0; mt < 2; mt++)
#pragma unroll
        for (int nt = 0; nt < NT32; nt++)
          acc[mt][nt] = MFMA32(af[mt], bfr[nt], acc[mt][nt]);
    }
  }

  // epilogue: 32x32 C/D map: col = lane&31, row = (reg&3) + 8*(reg>>2) + 4*hi
#pragma unroll
  for (int mt = 0; mt < 2; mt++) {
#pragma unroll
    for (int nt = 0; nt < NT32; nt++) {
      int col = bn * 128 + wcol + nt * 32 + lrow;
      float bv;
      if (MODE == 4) {
        int sec = col >> 10, hcol = col & 1023;  // sec is block-uniform
        bv = (sec == 0) ? b0[hcol] : (sec == 1) ? b1[hcol] : b2[hcol];
      } else {
        bv = b0[col];
      }
#pragma unroll
      for (int reg = 0; reg < 16; reg++) {
        int row = bm * 128 + wrow + mt * 32 + (reg & 3) + 8 * (reg >> 2) + 4 * hi;
        float v = acc[mt][nt][reg] + bv;
        if (MODE == 2) {
          // gelu(v) = v * sigmoid(2u); z = -(c1*v + c2*v^3) in log2 domain
          const float c1 = -2.3025850929940457f;           // -2*0.7978845608*log2e
          const float c2 = c1 * 0.044715f;
          float t2 = v * v;
          float z = v * (c1 + c2 * t2);
          float sg = 1.0f / (1.0f + __builtin_amdgcn_exp2f(z));
          ((u16*)outp)[(size_t)row * N + col] = f2b(v * sg);
        } else if (MODE == 3) {
          ((float*)outp)[(size_t)row * N + col] = v + resid[(size_t)row * N + col];
        } else if (MODE == 4) {
          int sec = col >> 10, hcol = col & 1023;
          int head = hcol >> 6, hd = hcol & 63;
          int bb = row >> 11, t = row & 2047;
          size_t hbase = ((size_t)bb * 16 + head) * 131072;
          u16* qout = (u16*)outp;
          if (sec == 0) {
            qout[hbase + qk_off(t, hd)] = f2b(v * scale);
          } else if (sec == 1) {
            (qout + 8388608)[hbase + qk_off(t, hd)] = f2b(v);
          } else {
            (qout + 16777216)[hbase + v_off(t, hd)] = f2b(v);
          }
        }
      }
    }
  }
}

// ---------------------------------------------------------------------------
// Flash attention v4 (unchanged from R3/R4). Causal, Q pre-scaled by log2e/32.
// Fixed-max exp2 softmax; row sums via ones-column MFMA; 128 q-rows/block;
// K/V staged cooperatively from fragment-ordered global layouts.
__global__ __launch_bounds__(256) void attn_kernel(
    const u16* __restrict__ Q, const u16* __restrict__ Kc,
    const u16* __restrict__ Vt, const float* __restrict__ x,
    float* __restrict__ x1, u16* __restrict__ xb1) {
  const int bh = blockIdx.x & 63;   // head-major: a head's 8 blocks share an XCD
  const int slot = blockIdx.x >> 6; // 0..7
  const int tid = threadIdx.x;
  const int wid = tid >> 6, lane = tid & 63;
  const int g = lane >> 4, c = lane & 15;
  const u16* Qh = Q + (size_t)bh * 131072;
  const u16* Kh = Kc + (size_t)bh * 131072;
  const u16* Vh = Vt + (size_t)bh * 131072;
  const int b = bh >> 4, head = bh & 15;

  __shared__ __attribute__((aligned(16))) u16 Ks[8192];  // 128 keys frag-order
  __shared__ __attribute__((aligned(16))) u16 Vs[8192];
  __shared__ __attribute__((aligned(16))) u16 P[4][32][72];

  bf16x8 ones;
#pragma unroll
  for (int i = 0; i < 8; i++) ones[i] = (__bf16)1.0f;

  const f32x4 zero4 = {0.f, 0.f, 0.f, 0.f};

  for (int phase = 0; phase < 2; ++phase) {
    const int bt = phase ? (15 - slot) : slot;
    const int q0b = bt * 128;
    const int q0 = q0b + wid * 32;
    const int kendw = q0 + 32;       // this wave needs keys < kendw
    const int nkt = bt + 1;          // 128-key tiles for the block

    bf16x8 qf[2][2];
#pragma unroll
    for (int mt = 0; mt < 2; mt++)
#pragma unroll
      for (int h = 0; h < 2; h++)
        qf[mt][h] = *(const bf16x8*)&Qh[(((q0 >> 4) + mt) * 2 + h) * 512 + lane * 8];

    f32x4 o[2][4];
    f32x4 lac[2];
#pragma unroll
    for (int mt = 0; mt < 2; mt++) {
      lac[mt] = zero4;
#pragma unroll
      for (int i = 0; i < 4; i++) o[mt][i] = zero4;
    }

    for (int kt = 0; kt < nkt; ++kt) {
      const int k0 = kt * 128;
      // cooperative stage: K,V 16KB each, contiguous in global (frag-order)
#pragma unroll
      for (int r2 = 0; r2 < 4; r2++) {
        int idx = (r2 * 256 + tid) * 8;  // u16 offset; LDS dest = uniform + lane*16B
        gld16(Kh + (size_t)k0 * 64 + idx, Ks + idx);
        gld16(Vh + (size_t)k0 * 64 + idx, Vs + idx);
      }
      __syncthreads();

#pragma unroll
      for (int s2 = 0; s2 < 2; ++s2) {
        const int k0s = k0 + s2 * 64;
        if (k0s < kendw) {  // wave-uniform; no barrier inside
          bf16x8 kf[4][2], vf[4][2];
#pragma unroll
          for (int nt = 0; nt < 4; nt++)
#pragma unroll
            for (int h = 0; h < 2; h++) {
              kf[nt][h] = *(const bf16x8*)&Ks[s2 * 4096 + (nt * 2 + h) * 512 + lane * 8];
              vf[nt][h] = *(const bf16x8*)&Vs[s2 * 4096 + (nt * 2 + h) * 512 + lane * 8];
            }

          f32x4 sv[2][4];
#pragma unroll
          for (int mt = 0; mt < 2; mt++)
#pragma unroll
            for (int nt = 0; nt < 4; nt++) sv[mt][nt] = zero4;
#pragma unroll
          for (int nt = 0; nt < 4; nt++)
#pragma unroll
            for (int mt = 0; mt < 2; mt++) {
              sv[mt][nt] = MFMA(qf[mt][0], kf[nt][0], sv[mt][nt]);
              sv[mt][nt] = MFMA(qf[mt][1], kf[nt][1], sv[mt][nt]);
            }

          if (k0s + 64 > q0) {  // wave-uniform; last needed sub-tile only
#pragma unroll
            for (int mt = 0; mt < 2; mt++)
#pragma unroll
              for (int rr = 0; rr < 4; rr++) {
                int q = q0 + mt * 16 + g * 4 + rr;
#pragma unroll
                for (int nt = 0; nt < 4; nt++)
                  if (k0s + nt * 16 + c > q) sv[mt][nt][rr] = -1e30f;
              }
          }

          // p = exp2(s); pack 4 -> one b64 LDS write (kk = 4c..4c+3)
#pragma unroll
          for (int mt = 0; mt < 2; mt++)
#pragma unroll
            for (int rr = 0; rr < 4; rr++) {
              union { u16x4 u; bf16x4 h; } pw;
#pragma unroll
              for (int nt = 0; nt < 4; nt++)
                pw.h[nt] = (__bf16)__builtin_amdgcn_exp2f(sv[mt][nt][rr]);
              *(u16x4*)&P[wid][mt * 16 + g * 4 + rr][4 * c] = pw.u;
            }

          asm volatile("s_waitcnt lgkmcnt(0)" ::: "memory");  // wave-private P RAW

#pragma unroll
          for (int mt = 0; mt < 2; mt++) {
            bf16x8 pf0 = *(const bf16x8*)&P[wid][mt * 16 + c][g * 8];
            bf16x8 pf1 = *(const bf16x8*)&P[wid][mt * 16 + c][32 + g * 8];
            lac[mt] = MFMA(pf0, ones, lac[mt]);
            lac[mt] = MFMA(pf1, ones, lac[mt]);
#pragma unroll
            for (int ot = 0; ot < 4; ot++) {
              f32x4 oo = MFMA(pf0, vf[ot][0], o[mt][ot]);
              o[mt][ot] = MFMA(pf1, vf[ot][1], oo);
            }
          }
        }
      }
      __syncthreads();  // before restaging Ks/Vs
    }

    // epilogue: O/l + residual
    float inv[2][4];
#pragma unroll
    for (int mt = 0; mt < 2; mt++)
#pragma unroll
      for (int rr = 0; rr < 4; rr++) inv[mt][rr] = 1.0f / lac[mt][rr];
#pragma unroll
    for (int mt = 0; mt < 2; mt++)
#pragma unroll
      for (int ot = 0; ot < 4; ot++)
#pragma unroll
        for (int rr = 0; rr < 4; rr++) {
          int t = q0 + mt * 16 + g * 4 + rr;
          int hd = ot * 16 + c;
          size_t xi = ((size_t)b * 2048 + t) * 1024 + head * 64 + hd;
          float v = x[xi] + o[mt][ot][rr] * inv[mt][rr];
          x1[xi] = v;
          xb1[xi] = f2b(v);
        }
  }
}

// ---------------------------------------------------------------------------
extern "C" void kernel_launch(void* const* d_in, const int* in_sizes, int n_in,
                              void* d_out, int out_size, void* d_ws, size_t ws_size,
                              hipStream_t stream) {
  (void)in_sizes; (void)n_in; (void)out_size; (void)ws_size;
  const float* x = (const float*)d_in[0];
  const float* Wq = (const float*)d_in[1];
  const float* bq = (const float*)d_in[2];
  const float* Wk = (const float*)d_in[3];
  const float* bk = (const float*)d_in[4];
  const float* Wv = (const float*)d_in[5];
  const float* bv = (const float*)d_in[6];
  const float* W1 = (const float*)d_in[7];
  const float* b1 = (const float*)d_in[8];
  const float* W2 = (const float*)d_in[9];
  const float* b2 = (const float*)d_in[10];

  char* ws = (char*)d_ws;
  size_t off = 0;
  auto alloc = [&](size_t bytes) {
    char* p = ws + off;
    off += (bytes + 255) & ~(size_t)255;
    return p;
  };
  u16* xb    = (u16*)alloc(8192ull * 1024 * 2);   // bf16(x)
  u16* Wqkvt = (u16*)alloc(3072ull * 1024 * 2);   // [3072][1024] bf16 (Wq|Wk|Wv rows)
  u16* W1t   = (u16*)alloc(4096ull * 1024 * 2);
  u16* W2t   = (u16*)alloc(1024ull * 4096 * 2);
  u16* Qb    = (u16*)alloc(3ull * 8192 * 1024 * 2);  // Q|K|V frag-ordered, contiguous
  float* x1  = (float*)alloc(8192ull * 1024 * 4); // x + attn (fp32 residual)
  u16* hb    = (u16*)alloc(8192ull * 4096 * 2);   // gelu(x1@W1+b1)
  u16* xb1   = xb;  // xb dead after QKV gemm; reuse for bf16(x1)
  u16* Kb    = Qb + 8388608;
  u16* Vtb   = Qb + 16777216;

  const float qscale = 1.4426950408889634f / 32.0f;  // log2e / sqrt(H)

  // 1. prep: x->bf16 + all weight transposes (one launch)
  prep_all<<<dim3(11264 + 8192), dim3(32, 8), 0, stream>>>(
      x, xb, Wq, Wk, Wv, W1, W2, Wqkvt, W1t, W2t);
  // 2. fused QKV projection (M=8192, N=3072, K=1024) -> frag-ordered Q/K/V
  gemm_bt<4, 4><<<dim3(24, 64), dim3(256), 0, stream>>>(
      xb, Wqkvt, bq, bk, bv, Qb, nullptr, 3072, 1024, qscale);
  // 3. attention + residual 1  (512 blocks; paired 128-row tiles)
  attn_kernel<<<dim3(512), dim3(256), 0, stream>>>(Qb, Kb, Vtb, x, x1, xb1);
  // 4. MLP1: gelu(x1 @ W1 + b1)  (M=8192, N=4096, K=1024)
  gemm_bt<2, 4><<<dim3(32, 64), dim3(256), 0, stream>>>(
      xb1, W1t, b1, nullptr, nullptr, hb, nullptr, 4096, 1024, 1.0f);
  // 5. MLP2 + residual 2 -> d_out (fp32), 8-wave blocks for occupancy
  gemm_bt<3, 8><<<dim3(8, 64), dim3(512), 0, stream>>>(
      hb, W2t, b2, nullptr, nullptr, d_out, x1, 1024, 4096, 1.0f);
}